// Round 1
// baseline (22.276 us; speedup 1.0000x reference)
//
#include <hip/hip_runtime.h>

#define PH 7
#define PW 7

__global__ void roipool_kernel(const float* __restrict__ feat,
                               const float* __restrict__ rois,
                               float* __restrict__ out,
                               int C, int H, int W, int R) {
    const int total = R * C * PH * PW;
    int idx = blockIdx.x * blockDim.x + threadIdx.x;
    if (idx >= total) return;

    const int j = idx % PW;
    const int i = (idx / PW) % PH;
    const int c = (idx / (PW * PH)) % C;
    const int r = idx / (PW * PH * C);

    const float* roi = rois + (size_t)r * 5;
    const int b = (int)roi[0];
    const float RATIO = 1.0f / 32.0f;
    // match jnp: floor(roi*RATIO) then clip to [0, W/H] as float
    const float x0 = fminf(fmaxf(floorf(roi[1] * RATIO), 0.0f), (float)W);
    const float y0 = fminf(fmaxf(floorf(roi[2] * RATIO), 0.0f), (float)H);
    const float x1 = fminf(fmaxf(floorf(roi[3] * RATIO), 0.0f), (float)W);
    const float y1 = fminf(fmaxf(floorf(roi[4] * RATIO), 0.0f), (float)H);
    const bool valid = (x1 > x0) && (y1 > y0);
    const float bin_h = (y1 - y0) * (1.0f / PH);
    const float bin_w = (x1 - x0) * (1.0f / PW);

    // jnp: (y0 + floor(i*bin_h)).astype(int32) -- values >= 0, trunc == floor
    int ys = (int)(y0 + floorf((float)i * bin_h));
    int ye = (int)(y0 + ceilf((float)(i + 1) * bin_h));
    int xs = (int)(x0 + floorf((float)j * bin_w));
    int xe = (int)(x0 + ceilf((float)(j + 1) * bin_w));
    ys = min(max(ys, 0), H);
    ye = min(max(ye, 0), H);
    xs = min(max(xs, 0), W);
    xe = min(max(xe, 0), W);

    float result = 0.0f;
    if (valid && (ye > ys) && (xe > xs)) {
        const float* base = feat + ((size_t)b * C + c) * (size_t)(H * W);
        float mm = -INFINITY;
        for (int y = ys; y < ye; ++y) {
            const float* row = base + (size_t)y * W;
            for (int x = xs; x < xe; ++x) {
                mm = fmaxf(mm, row[x]);
            }
        }
        result = mm;  // region values are finite
    }
    out[idx] = result;
}

extern "C" void kernel_launch(void* const* d_in, const int* in_sizes, int n_in,
                              void* d_out, int out_size, void* d_ws, size_t ws_size,
                              hipStream_t stream) {
    const float* feat = (const float*)d_in[0];
    const float* rois = (const float*)d_in[1];
    float* out = (float*)d_out;

    const int R = in_sizes[1] / 5;       // 128
    const int C = 256, H = 64, W = 64;   // per reference setup (N=4)

    const int total = R * C * PH * PW;
    const int block = 256;
    const int grid = (total + block - 1) / block;
    roipool_kernel<<<grid, block, 0, stream>>>(feat, rois, out, C, H, W, R);
}